// Round 1
// baseline (597.036 us; speedup 1.0000x reference)
//
#include <hip/hip_runtime.h>

#define NTOK 49
#define DIM  128
#define NH   4
#define HD   32
#define NWIN 8192
#define NWM  64

typedef short short8 __attribute__((ext_vector_type(8)));
typedef float f32x4  __attribute__((ext_vector_type(4)));

__device__ __forceinline__ short f2bf(float f) {
  unsigned u = __builtin_bit_cast(unsigned, f);
  u = (u + 0x7FFFu + ((u >> 16) & 1u)) >> 16;   // RNE round to bf16
  return (short)u;
}

__global__ void prep_weights(const float* __restrict__ qkv_w,
                             const float* __restrict__ proj_w,
                             short* __restrict__ wq, short* __restrict__ wp) {
  int i = blockIdx.x * 256 + threadIdx.x;            // grid covers 49152+16384 exactly
  if (i < 3 * DIM * DIM) wq[i] = f2bf(qkv_w[i]);
  else wp[i - 3 * DIM * DIM] = f2bf(proj_w[i - 3 * DIM * DIM]);
}

__global__ void prep_bm(const float* __restrict__ attn_mask,
                        const float* __restrict__ rpb_table,
                        const int* __restrict__ rpb_index,
                        float* __restrict__ bm) {
  int wm = blockIdx.x >> 2, h = blockIdx.x & 3;      // 256 blocks = 64 masks x 4 heads
  const float* mrow = attn_mask + wm * (NTOK * NTOK);
  float* dst = bm + blockIdx.x * (NTOK * NTOK);
  for (int i = threadIdx.x; i < NTOK * NTOK; i += 256)
    dst[i] = rpb_table[rpb_index[i] * NH + h] + mrow[i];
}

// LDS layout (59392 B total, static):
//   [0, 40960): 4 per-head bufs of 10240B: Q[64][40] (5120) | K[64][40] (5120);
//               P[64] rows, stride 72 el (9216B) OVERLAYS Q/K after S done (same wave).
//   [40960, 59392): Vt per head: [32][72 el] = 4608B each.
//   Y[64][136 el] (17408B) OVERLAYS the head-buf region (barrier-protected).
#define QK_S 40
#define P_S  72
#define VT_S 72
#define Y_S  136

template<bool USE_BM>
__global__ void __launch_bounds__(256, 2)
swin_attn(const float* __restrict__ x,
          const short* __restrict__ wq, const short* __restrict__ wp,
          const float* __restrict__ qkv_b, const float* __restrict__ proj_b,
          const float* __restrict__ bm,
          const int* __restrict__ rpb_index, const float* __restrict__ rpb_table,
          const float* __restrict__ attn_mask,
          float* __restrict__ out) {
  __shared__ __align__(16) char smem[59392];
  const int w    = blockIdx.x;
  const int tid  = threadIdx.x;
  const int h    = tid >> 6;          // wave id == head id
  const int lane = tid & 63;
  const int l16  = lane & 15;
  const int quad = lane >> 4;

  short* qh  = (short*)(smem + h * 10240);
  short* kh  = (short*)(smem + h * 10240 + 5120);
  short* ph  = (short*)(smem + h * 10240);           // overlays Q/K
  short* vth = (short*)(smem + 40960 + h * 4608);
  short* yb  = (short*)(smem);                        // overlays head bufs

  // ---- phase 0: x A-fragments (global -> regs, fp32 -> bf16) ----
  short8 af[4][4];
  const float* xw = x + (size_t)w * (NTOK * DIM);
  #pragma unroll
  for (int mt = 0; mt < 4; ++mt) {
    int row = mt * 16 + l16; if (row > 48) row = 48;  // clamp pad rows (finite garbage, never stored)
    #pragma unroll
    for (int ks = 0; ks < 4; ++ks) {
      const f32x4* p = (const f32x4*)(xw + row * DIM + ks * 32 + quad * 8);
      f32x4 f0 = p[0], f1 = p[1];
      short8 a;
      a[0]=f2bf(f0[0]); a[1]=f2bf(f0[1]); a[2]=f2bf(f0[2]); a[3]=f2bf(f0[3]);
      a[4]=f2bf(f1[0]); a[5]=f2bf(f1[1]); a[6]=f2bf(f1[2]); a[7]=f2bf(f1[3]);
      af[mt][ks] = a;
    }
  }

  const float scale = 0.17677669529663687f;  // 32^-0.5, folded into Q

  // ---- phase 1: QKV GEMM. chunk c: 0=Q,1=K,2=V; wave h handles channels c*128+h*32..+32 ----
  #pragma unroll
  for (int c = 0; c < 3; ++c) {
    const int o0 = c * DIM + h * HD;
    f32x4 acc[2][4];
    #pragma unroll
    for (int nt = 0; nt < 2; ++nt)
      #pragma unroll
      for (int mt = 0; mt < 4; ++mt) { f32x4 z = {0.f,0.f,0.f,0.f}; acc[nt][mt] = z; }
    #pragma unroll
    for (int ks = 0; ks < 4; ++ks) {
      short8 b0 = *(const short8*)(wq + (o0 + l16) * DIM + ks * 32 + quad * 8);
      short8 b1 = *(const short8*)(wq + (o0 + 16 + l16) * DIM + ks * 32 + quad * 8);
      #pragma unroll
      for (int mt = 0; mt < 4; ++mt) {
        acc[0][mt] = __builtin_amdgcn_mfma_f32_16x16x32_bf16(af[mt][ks], b0, acc[0][mt], 0, 0, 0);
        acc[1][mt] = __builtin_amdgcn_mfma_f32_16x16x32_bf16(af[mt][ks], b1, acc[1][mt], 0, 0, 0);
      }
    }
    #pragma unroll
    for (int nt = 0; nt < 2; ++nt) {
      float bias = qkv_b[o0 + nt * 16 + l16];
      #pragma unroll
      for (int mt = 0; mt < 4; ++mt)
        #pragma unroll
        for (int r = 0; r < 4; ++r) {
          int m = mt * 16 + quad * 4 + r;           // token (C-layout row)
          int d = nt * 16 + l16;                    // hd channel (C-layout col)
          float v = acc[nt][mt][r] + bias;
          if (c == 0)      qh[m * QK_S + d] = f2bf(v * scale);
          else if (c == 1) kh[m * QK_S + d] = f2bf(v);
          else             vth[d * VT_S + m] = f2bf(v);   // V transposed
        }
    }
  }

  // ---- phase 2: S = Q K^T (K-dim = 32 -> single MFMA k-step) ----
  f32x4 s[4][4];
  #pragma unroll
  for (int mt = 0; mt < 4; ++mt)
    #pragma unroll
    for (int nt = 0; nt < 4; ++nt) { f32x4 z = {0.f,0.f,0.f,0.f}; s[mt][nt] = z; }
  {
    short8 aQ[4], bK[4];
    #pragma unroll
    for (int mt = 0; mt < 4; ++mt) aQ[mt] = *(const short8*)(qh + (mt * 16 + l16) * QK_S + quad * 8);
    #pragma unroll
    for (int nt = 0; nt < 4; ++nt) bK[nt] = *(const short8*)(kh + (nt * 16 + l16) * QK_S + quad * 8);
    #pragma unroll
    for (int mt = 0; mt < 4; ++mt)
      #pragma unroll
      for (int nt = 0; nt < 4; ++nt)
        s[mt][nt] = __builtin_amdgcn_mfma_f32_16x16x32_bf16(aQ[mt], bK[nt], s[mt][nt], 0, 0, 0);
  }

  // ---- softmax (in-register, rows live across 16-lane groups) ----
  const int wm = w & (NWM - 1);
  const float* bmh = USE_BM ? bm + (size_t)(wm * NH + h) * (NTOK * NTOK) : nullptr;
  float rinv[4][4];
  #pragma unroll
  for (int mt = 0; mt < 4; ++mt) {
    #pragma unroll
    for (int r = 0; r < 4; ++r) {
      int m = mt * 16 + quad * 4 + r;
      #pragma unroll
      for (int nt = 0; nt < 4; ++nt) {
        int n = nt * 16 + l16;
        float v = s[mt][nt][r];
        if (n >= NTOK) v = -1e30f;                  // pad key columns -> P = 0
        else if (m < NTOK) {
          if (USE_BM) v += bmh[m * NTOK + n];
          else v += rpb_table[rpb_index[m * NTOK + n] * NH + h]
                  + attn_mask[(wm * NTOK + m) * NTOK + n];
        }
        s[mt][nt][r] = v;
      }
      float mx = fmaxf(fmaxf(s[mt][0][r], s[mt][1][r]), fmaxf(s[mt][2][r], s[mt][3][r]));
      mx = fmaxf(mx, __shfl_xor(mx, 1, 16));
      mx = fmaxf(mx, __shfl_xor(mx, 2, 16));
      mx = fmaxf(mx, __shfl_xor(mx, 4, 16));
      mx = fmaxf(mx, __shfl_xor(mx, 8, 16));
      float t = 0.f;
      #pragma unroll
      for (int nt = 0; nt < 4; ++nt) {
        float p = __expf(s[mt][nt][r] - mx);
        s[mt][nt][r] = p;
        t += p;
      }
      t += __shfl_xor(t, 1, 16);
      t += __shfl_xor(t, 2, 16);
      t += __shfl_xor(t, 4, 16);
      t += __shfl_xor(t, 8, 16);
      rinv[mt][r] = 1.0f / t;
      #pragma unroll
      for (int nt = 0; nt < 4; ++nt)
        ph[m * P_S + nt * 16 + l16] = f2bf(s[mt][nt][r]);   // unnormalized P (<=1)
    }
  }

  // ---- phase 3: Y = P V  (K-dim = 64 tokens -> 2 k-steps) ----
  f32x4 y[2][4];
  #pragma unroll
  for (int dt = 0; dt < 2; ++dt)
    #pragma unroll
    for (int mt = 0; mt < 4; ++mt) { f32x4 z = {0.f,0.f,0.f,0.f}; y[dt][mt] = z; }
  #pragma unroll
  for (int kt = 0; kt < 2; ++kt) {
    short8 aP[4], bV[2];
    #pragma unroll
    for (int mt = 0; mt < 4; ++mt) aP[mt] = *(const short8*)(ph + (mt * 16 + l16) * P_S + kt * 32 + quad * 8);
    #pragma unroll
    for (int dt = 0; dt < 2; ++dt) bV[dt] = *(const short8*)(vth + (dt * 16 + l16) * VT_S + kt * 32 + quad * 8);
    #pragma unroll
    for (int dt = 0; dt < 2; ++dt)
      #pragma unroll
      for (int mt = 0; mt < 4; ++mt)
        y[dt][mt] = __builtin_amdgcn_mfma_f32_16x16x32_bf16(aP[mt], bV[dt], y[dt][mt], 0, 0, 0);
  }
  #pragma unroll
  for (int dt = 0; dt < 2; ++dt)
    #pragma unroll
    for (int mt = 0; mt < 4; ++mt)
      #pragma unroll
      for (int r = 0; r < 4; ++r)
        y[dt][mt][r] *= rinv[mt][r];                // softmax denominator

  __syncthreads();   // all P reads done before Y overlays the head-buf region
  #pragma unroll
  for (int dt = 0; dt < 2; ++dt)
    #pragma unroll
    for (int mt = 0; mt < 4; ++mt)
      #pragma unroll
      for (int r = 0; r < 4; ++r) {
        int m = mt * 16 + quad * 4 + r;
        yb[m * Y_S + h * HD + dt * 16 + l16] = f2bf(y[dt][mt][r]);
      }
  __syncthreads();   // Y complete before proj reads it cross-wave

  // ---- phase 4: out = Y proj_w^T + proj_b; wave h handles out cols [32h, 32h+32) ----
  {
    const int o0 = h * 32;
    f32x4 oa[2][4];
    #pragma unroll
    for (int nt = 0; nt < 2; ++nt)
      #pragma unroll
      for (int mt = 0; mt < 4; ++mt) { f32x4 z = {0.f,0.f,0.f,0.f}; oa[nt][mt] = z; }
    #pragma unroll
    for (int ks = 0; ks < 4; ++ks) {
      short8 aY[4];
      #pragma unroll
      for (int mt = 0; mt < 4; ++mt) aY[mt] = *(const short8*)(yb + (mt * 16 + l16) * Y_S + ks * 32 + quad * 8);
      short8 b0 = *(const short8*)(wp + (o0 + l16) * DIM + ks * 32 + quad * 8);
      short8 b1 = *(const short8*)(wp + (o0 + 16 + l16) * DIM + ks * 32 + quad * 8);
      #pragma unroll
      for (int mt = 0; mt < 4; ++mt) {
        oa[0][mt] = __builtin_amdgcn_mfma_f32_16x16x32_bf16(aY[mt], b0, oa[0][mt], 0, 0, 0);
        oa[1][mt] = __builtin_amdgcn_mfma_f32_16x16x32_bf16(aY[mt], b1, oa[1][mt], 0, 0, 0);
      }
    }
    float pb0 = proj_b[o0 + l16], pb1 = proj_b[o0 + 16 + l16];
    float* ow = out + (size_t)w * (NTOK * DIM);
    #pragma unroll
    for (int nt = 0; nt < 2; ++nt) {
      float pb = nt ? pb1 : pb0;
      #pragma unroll
      for (int mt = 0; mt < 4; ++mt)
        #pragma unroll
        for (int r = 0; r < 4; ++r) {
          int m = mt * 16 + quad * 4 + r;
          if (m < NTOK) ow[m * DIM + o0 + nt * 16 + l16] = oa[nt][mt][r] + pb;
        }
    }
  }
}

extern "C" void kernel_launch(void* const* d_in, const int* in_sizes, int n_in,
                              void* d_out, int out_size, void* d_ws, size_t ws_size,
                              hipStream_t stream) {
  const float* x         = (const float*)d_in[0];
  const float* attn_mask = (const float*)d_in[1];
  const float* qkv_w     = (const float*)d_in[2];
  const float* qkv_b     = (const float*)d_in[3];
  const float* proj_w    = (const float*)d_in[4];
  const float* proj_b    = (const float*)d_in[5];
  const float* rpb_table = (const float*)d_in[6];
  const int*   rpb_index = (const int*)d_in[7];
  float* out = (float*)d_out;

  short* wq = (short*)d_ws;                          // 49152 bf16
  short* wp = wq + 3 * DIM * DIM;                    // 16384 bf16
  float* bmp = (float*)((char*)d_ws + 131072);       // fused bias+mask [64][4][49][49] f32
  size_t need = 131072 + (size_t)NWM * NH * NTOK * NTOK * sizeof(float);

  prep_weights<<<256, 256, 0, stream>>>(qkv_w, proj_w, wq, wp);
  if (ws_size >= need) {
    prep_bm<<<256, 256, 0, stream>>>(attn_mask, rpb_table, rpb_index, bmp);
    swin_attn<true><<<NWIN, 256, 0, stream>>>(x, wq, wp, qkv_b, proj_b, bmp,
                                              rpb_index, rpb_table, attn_mask, out);
  } else {
    swin_attn<false><<<NWIN, 256, 0, stream>>>(x, wq, wp, qkv_b, proj_b, nullptr,
                                               rpb_index, rpb_table, attn_mask, out);
  }
}